// Round 16
// baseline (106.373 us; speedup 1.0000x reference)
//
#include <hip/hip_runtime.h>
#include <hip/hip_fp16.h>

// DRR ray-casting for MI355X — round 16.
// r15: dot2 landed (main 50.2 -> 46.3, total 80.1). Main is at the floor of
// the 4-gather/sample structure. r16 changes the floor: quad array
// vq[z][j][i] = 2x2 (x,y) corner block as 4xf16 (8B) -> 2 dwordx2 gathers
// per trilinear sample (z0,z1); instruction count AND distinct-row footprint
// halve. Needs 136.3 MB ws -> tiered: quad / pair (r15-proven) / f32.

static __device__ __constant__ float kPX     = 1.6875f;
static __device__ __constant__ float kPIERCE = 216.0f;
static __device__ __constant__ float kSAD    = 742.5f;
static __device__ __constant__ float kDAD    = 517.15f;

#define VOL_BYTES   (256u * 256u * 256u * 4u)
#define PAIR_R      258u
#define PAIR_ELEMS  (256u * 256u * PAIR_R)
#define PAIR_BYTES  (PAIR_ELEMS * 4u)
#define QJ          258u
#define QZ          66564u                    // 258*258
#define QUAD_ELEMS  (256u * QJ * QJ)          // uint2 elements (z,j,i)
#define QUAD_BYTES  ((size_t)QUAD_ELEMS * 8u)

typedef __fp16 half2_raw __attribute__((ext_vector_type(2)));

__device__ __forceinline__ unsigned pack_u(float lo, float hi) {
    return __builtin_bit_cast(unsigned,
        __halves2half2(__float2half(lo), __float2half(hi)));
}

__global__ void drr_init_mm(unsigned* mm) {
    int i = threadIdx.x;
    if (i < 4) mm[i] = (i & 1) ? 0u : 0x7F800000u;
}

// ============ QUAD tier ====================================================
// pack_q: vol[x][y][z] -> vq[z][j][i] quad: lo=(v[i-1][j-1],v[i][j-1]),
// hi=(v[i-1][j],v[i][j]); zero-padded for x,y outside [0,256).
// Block: fixed j, i-tile (64), z-tile (64). Grid 258*5*4 = 5160.
__global__ __launch_bounds__(256) void drr_pack_q(const float* __restrict__ vol,
                                                  uint2* __restrict__ vq,
                                                  float* __restrict__ raw) {
    const int bid = blockIdx.x;
    if (bid < 4096 && threadIdx.x < 32)
        raw[(bid << 5) + threadIdx.x] = 0.0f;

    const int j  = bid / 20;
    const int t  = bid % 20;
    const int i0 = (t % 5) << 6;          // 0,64,128,192,256
    const int z0 = (t / 5) << 6;

    // tile[ysel][xrow][z]: ysel 0 -> y=j-1, 1 -> y=j ; xrow covers x=i0-1..i0+63
    __shared__ float tile[2][65][65];     // z-pad 65 to spread banks

    const int rr = threadIdx.x >> 4;      // 0..15
    const int cc = threadIdx.x & 15;      // float4 over z
    for (int r = rr; r < 130; r += 16) {
        const int ysel = (r >= 65) ? 1 : 0;
        const int xrow = r - ysel * 65;
        const int x = i0 - 1 + xrow;
        const int y = j - 1 + ysel;
        float4 f = make_float4(0.0f, 0.0f, 0.0f, 0.0f);
        if ((unsigned)x < 256u && (unsigned)y < 256u)
            f = *(const float4*)&vol[(x << 16) | (y << 8) | (z0 + (cc << 2))];
        tile[ysel][xrow][(cc << 2) + 0] = f.x;
        tile[ysel][xrow][(cc << 2) + 1] = f.y;
        tile[ysel][xrow][(cc << 2) + 2] = f.z;
        tile[ysel][xrow][(cc << 2) + 3] = f.w;
    }
    __syncthreads();

    const int li = threadIdx.x & 63;
    const int zz = threadIdx.x >> 6;      // 0..3
    const int i  = i0 + li;
    if (i < 258) {
        for (int z = zz; z < 64; z += 4) {
            const unsigned lo = pack_u(tile[0][li][z], tile[0][li + 1][z]);
            const unsigned hi = pack_u(tile[1][li][z], tile[1][li + 1][z]);
            vq[(size_t)(z0 + z) * QZ + (unsigned)j * QJ + i] = make_uint2(lo, hi);
        }
    }
}

// ============ shared geometry ==============================================
__device__ __forceinline__ void slab(float s, float r, float lo, float hi,
                                     float& tlo, float& thi) {
    if (fabsf(r) > 1e-8f) {
        const float inv = 1.0f / r;
        const float ta  = (lo - s) * inv;
        const float tb  = (hi - s) * inv;
        tlo = fmaxf(tlo, fminf(ta, tb));
        thi = fminf(thi, fmaxf(ta, tb));
    } else if (s < lo || s > hi) {
        tlo = 2.0f; thi = -1.0f;
    }
}

struct RayCfg {
    float rx, ry, rz, length;
    int k_lo, k_hi;
    int s_lo, s_hi;
};

__device__ __forceinline__ void cfg_windows(float sx, float sy, float sz, RayCfg& c) {
    float tlo = 0.0f, thi = 1.0f;
    slab(sx, c.rx, -1.02f, 256.02f, tlo, thi);
    slab(sy, c.ry, -1.02f, 256.02f, tlo, thi);
    slab(sz, c.rz, -1.02f, 256.02f, tlo, thi);
    c.k_lo = 0; c.k_hi = -1;
    if (thi >= tlo) {
        c.k_lo = max(0,   (int)ceilf(tlo * 255.0f - 1e-3f));
        c.k_hi = min(255, (int)floorf(thi * 255.0f + 1e-3f));
    }
    float slo = 0.0f, shi = 1.0f;
    slab(sx, c.rx, 0.01f, 254.99f, slo, shi);
    slab(sy, c.ry, 0.01f, 254.99f, slo, shi);
    slab(sz, c.rz, 0.01f, 254.99f, slo, shi);
    c.s_lo = 1; c.s_hi = -1;
    if (shi >= slo) {
        c.s_lo = (int)ceilf(slo * 255.0f + 1e-3f);
        c.s_hi = (int)floorf(shi * 255.0f - 1e-3f);
    }
}

__device__ __forceinline__ void ray_setup2(const float* __restrict__ batch,
                                           int b, int u, int v0,
                                           float& sx, float& sy, float& sz,
                                           RayCfg& A, RayCfg& B) {
    const float a  = batch[b * 6 + 0];
    const float be = batch[b * 6 + 1];
    const float g  = batch[b * 6 + 2];
    const float tx = batch[b * 6 + 3];
    const float ty = batch[b * 6 + 4];
    const float tz = batch[b * 6 + 5];

    float sa, ca, sb, cb, sg, cg;
    sincosf(a, &sa, &ca);
    sincosf(be, &sb, &cb);
    sincosf(g, &sg, &cg);

    const float R00 = ca * cb;
    const float R01 = ca * sb * sg - sa * cg;
    const float R02 = sa * sg + ca * sb * cg;
    const float R10 = sa * cb;
    const float R11 = ca * cg + sa * sb * sg;
    const float R12 = sa * sb * cg - ca * sg;
    const float R20 = -sb;
    const float R21 = cb * sg;
    const float R22 = cb * cg;

    sx = 128.0f + tx + kSAD * R02;
    sy = 128.0f + ty + kSAD * R12;
    sz = 128.0f + tz + kSAD * R22;

    const float uu = u * kPX - kPIERCE;
    const float vv = v0 * kPX - kPIERCE;
    A.rx = uu * R00 + vv * R01 - (kSAD + kDAD) * R02;
    A.ry = uu * R10 + vv * R11 - (kSAD + kDAD) * R12;
    A.rz = uu * R20 + vv * R21 - (kSAD + kDAD) * R22;
    B.rx = A.rx + kPX * R01;
    B.ry = A.ry + kPX * R11;
    B.rz = A.rz + kPX * R21;
    A.length = sqrtf(A.rx * A.rx + A.ry * A.ry + A.rz * A.rz);
    B.length = sqrtf(B.rx * B.rx + B.ry * B.ry + B.rz * B.rz);
    cfg_windows(sx, sy, sz, A);
    cfg_windows(sx, sy, sz, B);
}

__device__ __forceinline__ float xdot(unsigned q, half2_raw w) {
    return __builtin_amdgcn_fdot2(__builtin_bit_cast(half2_raw, q), w, 0.0f, false);
}

// ---- quad samplers: 2 dwordx2 gathers per sample ----
__device__ __forceinline__ float triq_fast(const uint2* __restrict__ vq,
                                           float sx, float sy, float sz,
                                           const RayCfg& c, float t) {
    const float px = fmaf(t, c.rx, sx);
    const float py = fmaf(t, c.ry, sy);
    const float pz = fmaf(t, c.rz, sz);
    const float fx = floorf(px), fy = floorf(py), fz = floorf(pz);
    const int ix = (int)fx, iy = (int)fy, iz = (int)fz;
    const float wx = px - fx, wy = py - fy, wz = pz - fz;

    const size_t base = (size_t)iz * QZ + (unsigned)(iy + 1) * QJ + (unsigned)(ix + 1);
    const uint2 qa = vq[base];            // z0: lo=(x0,x1)@y0, hi=(x0,x1)@y1
    const uint2 qb = vq[base + QZ];       // z1

    const half2_raw wxh = __builtin_amdgcn_cvt_pkrtz(1.0f - wx, wx);
    const float a0 = xdot(qa.x, wxh), a1 = xdot(qa.y, wxh);
    const float b0 = xdot(qb.x, wxh), b1 = xdot(qb.y, wxh);

    const float wy0 = 1.0f - wy, wz0 = 1.0f - wz;
    return (a0 * wy0 + a1 * wy) * wz0 + (b0 * wy0 + b1 * wy) * wz;
}

__device__ __forceinline__ float triq_slow(const uint2* __restrict__ vq,
                                           float sx, float sy, float sz,
                                           const RayCfg& c, float t) {
    const float px = fmaf(t, c.rx, sx);
    const float py = fmaf(t, c.ry, sy);
    const float pz = fmaf(t, c.rz, sz);
    const float fx = floorf(px), fy = floorf(py), fz = floorf(pz);
    const int ix = (int)fx, iy = (int)fy, iz = (int)fz;
    const float wx = px - fx, wy = py - fy, wz = pz - fz;

    const float mx0 = ((unsigned)ix       < 256u) ? 1.0f : 0.0f;
    const float mx1 = ((unsigned)(ix + 1) < 256u) ? 1.0f : 0.0f;
    const float my0 = ((unsigned)iy       < 256u) ? 1.0f : 0.0f;
    const float my1 = ((unsigned)(iy + 1) < 256u) ? 1.0f : 0.0f;
    const float mz0 = ((unsigned)iz       < 256u) ? 1.0f : 0.0f;
    const float mz1 = ((unsigned)(iz + 1) < 256u) ? 1.0f : 0.0f;

    const int i  = min(max(ix + 1, 0), 257);
    const int jj = min(max(iy + 1, 0), 257);
    const int z0 = min(max(iz,     0), 255);
    const int z1 = min(max(iz + 1, 0), 255);

    const uint2 qa = vq[(size_t)z0 * QZ + (unsigned)jj * QJ + i];
    const uint2 qb = vq[(size_t)z1 * QZ + (unsigned)jj * QJ + i];

    const half2_raw wxh = __builtin_amdgcn_cvt_pkrtz((1.0f - wx) * mx0, wx * mx1);
    const float a0 = xdot(qa.x, wxh), a1 = xdot(qa.y, wxh);
    const float b0 = xdot(qb.x, wxh), b1 = xdot(qb.y, wxh);

    const float wy0 = (1.0f - wy) * my0, wy1 = wy * my1;
    const float wz0 = (1.0f - wz) * mz0, wz1 = wz * mz1;
    return (a0 * wy0 + a1 * wy1) * wz0 + (b0 * wy0 + b1 * wy1) * wz1;
}

// main_q: geometry identical to proven pk3 (4096 = 1024 tiles x 4 k-quarters).
__global__ __launch_bounds__(256, 8) void drr_main_q(const uint2* __restrict__ vq,
                                                     const float* __restrict__ batch,
                                                     float* __restrict__ raw) {
    const int tid  = threadIdx.x;
    const int lane = tid & 63;
    const int seg  = tid >> 6;

    const int kq   = blockIdx.x & 3;
    const int tile = blockIdx.x >> 2;
    const int b    = tile >> 9;
    const int ti   = tile & 511;
    const int u    = ((ti & 15) << 4) + (lane & 15);
    const int v0   = ((ti >> 4) << 3) + ((lane >> 4) << 1);

    float sx, sy, sz;
    RayCfg A, B;
    ray_setup2(batch, b, u, v0, sx, sy, sz, A, B);

    const int klo = min(A.k_lo, B.k_lo);
    const int khi = max(A.k_hi, B.k_hi);
    const int slo = max(A.s_lo, B.s_lo);
    const int shi = min(A.s_hi, B.s_hi);

    const float tstep = 1.0f / 255.0f;
    float sA = 0.0f, sB = 0.0f;
    for (int k = klo + (kq << 2) + seg; k <= khi; k += 16) {
        const float t = (float)k * tstep;
        if (k >= slo && k <= shi) {
            sA += triq_fast(vq, sx, sy, sz, A, t);
            sB += triq_fast(vq, sx, sy, sz, B, t);
        } else {
            sA += triq_slow(vq, sx, sy, sz, A, t);
            sB += triq_slow(vq, sx, sy, sz, B, t);
        }
    }

    __shared__ float pA[4][64], pB[4][64];
    pA[seg][lane] = sA;
    pB[seg][lane] = sB;
    __syncthreads();

    if (tid < 64) {
        const float tA = pA[0][lane] + pA[1][lane] + pA[2][lane] + pA[3][lane];
        const float tB = pB[0][lane] + pB[1][lane] + pB[2][lane] + pB[3][lane];
        if (tA != 0.0f)
            atomicAdd(&raw[(b << 16) + (v0 << 8) + u],       tA * (A.length * (1.0f / 256.0f)));
        if (tB != 0.0f)
            atomicAdd(&raw[(b << 16) + ((v0 + 1) << 8) + u], tB * (B.length * (1.0f / 256.0f)));
    }
}

// ============ PAIR tier (r15 proven, 80.1 us) ==============================
__global__ __launch_bounds__(256) void drr_pack(const float* __restrict__ vol,
                                                __half2* __restrict__ vhp,
                                                float* __restrict__ raw) {
    const int bid = blockIdx.x;
    if (threadIdx.x < 32)
        raw[(bid << 5) + threadIdx.x] = 0.0f;

    __shared__ float tile[65][65];
    const int y    = bid >> 4;
    const int t4   = bid & 15;
    const int x0   = (t4 & 3) << 6;
    const int z0   = (t4 >> 2) << 6;

    const int rr = threadIdx.x >> 4;
    const int cc = threadIdx.x & 15;
    #pragma unroll
    for (int base = 0; base < 80; base += 16) {
        const int r = base + rr;
        if (r < 65) {
            const int x = x0 - 1 + r;
            float4 f = make_float4(0.0f, 0.0f, 0.0f, 0.0f);
            if (x >= 0)
                f = *(const float4*)&vol[(x << 16) | (y << 8) | (z0 + (cc << 2))];
            tile[r][(cc << 2) + 0] = f.x;
            tile[r][(cc << 2) + 1] = f.y;
            tile[r][(cc << 2) + 2] = f.z;
            tile[r][(cc << 2) + 3] = f.w;
        }
    }
    __syncthreads();

    const int lane = threadIdx.x & 63;
    const int row4 = threadIdx.x >> 6;
    for (int r = row4; r < 64; r += 4) {
        const int z = z0 + r;
        const unsigned base = (unsigned)((z << 8) | y) * PAIR_R;
        vhp[base + x0 + lane] =
            __halves2half2(__float2half(tile[lane][r]), __float2half(tile[lane + 1][r]));
    }
    if ((t4 & 3) == 3) {
        for (int r = row4; r < 64; r += 4) {
            const int z = z0 + r;
            const unsigned base = (unsigned)((z << 8) | y) * PAIR_R;
            if (lane == 0) {
                vhp[base + 256] = __halves2half2(__float2half(tile[64][r]), __float2half(0.0f));
                vhp[base + 257] = __halves2half2(__float2half(0.0f), __float2half(0.0f));
            }
        }
    }
}

__device__ __forceinline__ float xdoth(__half2 q, half2_raw w) {
    return __builtin_amdgcn_fdot2(__builtin_bit_cast(half2_raw, q), w, 0.0f, false);
}

__device__ __forceinline__ float tri_fast(const __half2* __restrict__ vhp,
                                          float sx, float sy, float sz,
                                          const RayCfg& c, float t) {
    const float px = fmaf(t, c.rx, sx);
    const float py = fmaf(t, c.ry, sy);
    const float pz = fmaf(t, c.rz, sz);
    const float fx = floorf(px), fy = floorf(py), fz = floorf(pz);
    const int ix = (int)fx, iy = (int)fy, iz = (int)fz;
    const float wx = px - fx, wy = py - fy, wz = pz - fz;

    const unsigned base = (unsigned)iz * 66048u + (unsigned)iy * 258u + (unsigned)(ix + 1);
    const __half2 q00 = vhp[base];
    const __half2 q01 = vhp[base + 66048u];
    const __half2 q10 = vhp[base + 258u];
    const __half2 q11 = vhp[base + 66306u];

    const half2_raw wxh = __builtin_amdgcn_cvt_pkrtz(1.0f - wx, wx);
    const float a00 = xdoth(q00, wxh);
    const float a01 = xdoth(q01, wxh);
    const float a10 = xdoth(q10, wxh);
    const float a11 = xdoth(q11, wxh);

    const float wy0 = 1.0f - wy, wz0 = 1.0f - wz;
    return (a00 * wz0 + a01 * wz) * wy0 + (a10 * wz0 + a11 * wz) * wy;
}

__device__ __forceinline__ float tri_slow(const __half2* __restrict__ vhp,
                                          float sx, float sy, float sz,
                                          const RayCfg& c, float t) {
    const float px = fmaf(t, c.rx, sx);
    const float py = fmaf(t, c.ry, sy);
    const float pz = fmaf(t, c.rz, sz);
    const float fx = floorf(px), fy = floorf(py), fz = floorf(pz);
    const int ix = (int)fx, iy = (int)fy, iz = (int)fz;
    const float wx = px - fx, wy = py - fy, wz = pz - fz;

    const float mx0 = ((unsigned)ix       < 256u) ? 1.0f : 0.0f;
    const float mx1 = ((unsigned)(ix + 1) < 256u) ? 1.0f : 0.0f;
    const float my0 = ((unsigned)iy       < 256u) ? 1.0f : 0.0f;
    const float my1 = ((unsigned)(iy + 1) < 256u) ? 1.0f : 0.0f;
    const float mz0 = ((unsigned)iz       < 256u) ? 1.0f : 0.0f;
    const float mz1 = ((unsigned)(iz + 1) < 256u) ? 1.0f : 0.0f;

    const int i  = min(max(ix + 1, 0), 257);
    const int y0 = min(max(iy,     0), 255);
    const int y1 = min(max(iy + 1, 0), 255);
    const int z0 = min(max(iz,     0), 255);
    const int z1 = min(max(iz + 1, 0), 255);

    const unsigned zt0 = (unsigned)z0 * 66048u;
    const unsigned zt1 = (unsigned)z1 * 66048u;
    const unsigned yt0 = (unsigned)y0 * 258u;
    const unsigned yt1 = (unsigned)y1 * 258u;

    const __half2 q00 = vhp[zt0 + yt0 + i];
    const __half2 q01 = vhp[zt1 + yt0 + i];
    const __half2 q10 = vhp[zt0 + yt1 + i];
    const __half2 q11 = vhp[zt1 + yt1 + i];

    const half2_raw wxh = __builtin_amdgcn_cvt_pkrtz((1.0f - wx) * mx0, wx * mx1);
    const float a00 = xdoth(q00, wxh);
    const float a01 = xdoth(q01, wxh);
    const float a10 = xdoth(q10, wxh);
    const float a11 = xdoth(q11, wxh);

    const float wy0 = (1.0f - wy) * my0, wy1 = wy * my1;
    const float wz0 = (1.0f - wz) * mz0, wz1 = wz * mz1;
    return (a00 * wz0 + a01 * wz1) * wy0 + (a10 * wz0 + a11 * wz1) * wy1;
}

__global__ __launch_bounds__(256, 8) void drr_main_pk3(const __half2* __restrict__ vhp,
                                                       const float* __restrict__ batch,
                                                       float* __restrict__ raw) {
    const int tid  = threadIdx.x;
    const int lane = tid & 63;
    const int seg  = tid >> 6;

    const int kq   = blockIdx.x & 3;
    const int tile = blockIdx.x >> 2;
    const int b    = tile >> 9;
    const int ti   = tile & 511;
    const int u    = ((ti & 15) << 4) + (lane & 15);
    const int v0   = ((ti >> 4) << 3) + ((lane >> 4) << 1);

    float sx, sy, sz;
    RayCfg A, B;
    ray_setup2(batch, b, u, v0, sx, sy, sz, A, B);

    const int klo = min(A.k_lo, B.k_lo);
    const int khi = max(A.k_hi, B.k_hi);
    const int slo = max(A.s_lo, B.s_lo);
    const int shi = min(A.s_hi, B.s_hi);

    const float tstep = 1.0f / 255.0f;
    float sA = 0.0f, sB = 0.0f;
    for (int k = klo + (kq << 2) + seg; k <= khi; k += 16) {
        const float t = (float)k * tstep;
        if (k >= slo && k <= shi) {
            sA += tri_fast(vhp, sx, sy, sz, A, t);
            sB += tri_fast(vhp, sx, sy, sz, B, t);
        } else {
            sA += tri_slow(vhp, sx, sy, sz, A, t);
            sB += tri_slow(vhp, sx, sy, sz, B, t);
        }
    }

    __shared__ float pA[4][64], pB[4][64];
    pA[seg][lane] = sA;
    pB[seg][lane] = sB;
    __syncthreads();

    if (tid < 64) {
        const float tA = pA[0][lane] + pA[1][lane] + pA[2][lane] + pA[3][lane];
        const float tB = pB[0][lane] + pB[1][lane] + pB[2][lane] + pB[3][lane];
        if (tA != 0.0f)
            atomicAdd(&raw[(b << 16) + (v0 << 8) + u],       tA * (A.length * (1.0f / 256.0f)));
        if (tB != 0.0f)
            atomicAdd(&raw[(b << 16) + ((v0 + 1) << 8) + u], tB * (B.length * (1.0f / 256.0f)));
    }
}

// ============ minmax / norm (r14 proven, no contended atomics) =============
__global__ __launch_bounds__(256) void drr_minmax(const float* __restrict__ raw,
                                                  float* __restrict__ part) {
    __shared__ float smn[4], smx[4];
    const int gid = blockIdx.x * 256 + threadIdx.x;
    const float x = raw[gid];
    float mn = x, mx = x;
    #pragma unroll
    for (int off = 32; off >= 1; off >>= 1) {
        mn = fminf(mn, __shfl_xor(mn, off));
        mx = fmaxf(mx, __shfl_xor(mx, off));
    }
    if ((threadIdx.x & 63) == 0) {
        smn[threadIdx.x >> 6] = mn;
        smx[threadIdx.x >> 6] = mx;
    }
    __syncthreads();
    if (threadIdx.x == 0) {
        part[2 * blockIdx.x + 0] = fminf(fminf(smn[0], smn[1]), fminf(smn[2], smn[3]));
        part[2 * blockIdx.x + 1] = fmaxf(fmaxf(smx[0], smx[1]), fmaxf(smx[2], smx[3]));
    }
}

__global__ __launch_bounds__(256) void drr_norm(float* __restrict__ img,
                                                const float* __restrict__ part) {
    __shared__ float smn[4], smx[4], fmn, fmx;
    const int b = blockIdx.x >> 8;
    const int pi = (b << 8) + threadIdx.x;
    float mn = part[2 * pi + 0];
    float mx = part[2 * pi + 1];
    #pragma unroll
    for (int off = 32; off >= 1; off >>= 1) {
        mn = fminf(mn, __shfl_xor(mn, off));
        mx = fmaxf(mx, __shfl_xor(mx, off));
    }
    if ((threadIdx.x & 63) == 0) {
        smn[threadIdx.x >> 6] = mn;
        smx[threadIdx.x >> 6] = mx;
    }
    __syncthreads();
    if (threadIdx.x == 0) {
        fmn = fminf(fminf(smn[0], smn[1]), fminf(smn[2], smn[3]));
        fmx = fmaxf(fmaxf(smx[0], smx[1]), fmaxf(smx[2], smx[3]));
    }
    __syncthreads();

    const int gid = blockIdx.x * 256 + threadIdx.x;
    const float inv = 1.0f / (fmx - fmn);
    img[gid] = 1.0f - (img[gid] - fmn) * inv;
}

// ============ f32 tier (smallest ws) =======================================
__global__ __launch_bounds__(256) void drr_transpose(const float* __restrict__ vol,
                                                     float* __restrict__ volt) {
    __shared__ float tile[64][65];
    const int bid  = blockIdx.x;
    const int y    = bid >> 4;
    const int t4   = bid & 15;
    const int x0   = (t4 & 3) << 6;
    const int z0   = (t4 >> 2) << 6;
    const int lane = threadIdx.x & 63;
    const int row4 = threadIdx.x >> 6;

    #pragma unroll
    for (int i = 0; i < 16; ++i) {
        const int xr = (i << 2) + row4;
        tile[xr][lane] = vol[((x0 + xr) << 16) | (y << 8) | (z0 + lane)];
    }
    __syncthreads();
    #pragma unroll
    for (int i = 0; i < 16; ++i) {
        const int zr = (i << 2) + row4;
        volt[((z0 + zr) << 16) | (y << 8) | (x0 + lane)] = tile[lane][zr];
    }
}

__device__ __forceinline__ float tri_sample_f32(const float* __restrict__ vol,
                                                float sx, float sy, float sz,
                                                const RayCfg& c, float t) {
    const float px = fmaf(t, c.rx, sx);
    const float py = fmaf(t, c.ry, sy);
    const float pz = fmaf(t, c.rz, sz);
    const float fx = floorf(px), fy = floorf(py), fz = floorf(pz);
    const int ix = (int)fx, iy = (int)fy, iz = (int)fz;
    const float wx = px - fx, wy = py - fy, wz = pz - fz;
    const float mx0 = ((unsigned)ix       < 256u) ? 1.0f : 0.0f;
    const float mx1 = ((unsigned)(ix + 1) < 256u) ? 1.0f : 0.0f;
    const float my0 = ((unsigned)iy       < 256u) ? 1.0f : 0.0f;
    const float my1 = ((unsigned)(iy + 1) < 256u) ? 1.0f : 0.0f;
    const float mz0 = ((unsigned)iz       < 256u) ? 1.0f : 0.0f;
    const float mz1 = ((unsigned)(iz + 1) < 256u) ? 1.0f : 0.0f;
    const unsigned X0 = (unsigned)ix & 255u, X1 = (unsigned)(ix + 1) & 255u;
    const unsigned Y0 = ((unsigned)iy & 255u) << 8, Y1 = ((unsigned)(iy + 1) & 255u) << 8;
    const unsigned Z0 = ((unsigned)iz & 255u) << 16, Z1 = ((unsigned)(iz + 1) & 255u) << 16;
    const float v000 = vol[Z0 | Y0 | X0];
    const float v001 = vol[Z1 | Y0 | X0];
    const float v010 = vol[Z0 | Y1 | X0];
    const float v011 = vol[Z1 | Y1 | X0];
    const float v100 = vol[Z0 | Y0 | X1];
    const float v101 = vol[Z1 | Y0 | X1];
    const float v110 = vol[Z0 | Y1 | X1];
    const float v111 = vol[Z1 | Y1 | X1];
    const float wx0 = (1.0f - wx) * mx0, wx1 = wx * mx1;
    const float wy0 = (1.0f - wy) * my0, wy1 = wy * my1;
    const float wz0 = (1.0f - wz) * mz0, wz1 = wz * mz1;
    const float c00 = v000 * wz0 + v001 * wz1;
    const float c01 = v010 * wz0 + v011 * wz1;
    const float c10 = v100 * wz0 + v101 * wz1;
    const float c11 = v110 * wz0 + v111 * wz1;
    return (c00 * wy0 + c01 * wy1) * wx0 + (c10 * wy0 + c11 * wy1) * wx1;
}

__global__ __launch_bounds__(256, 4) void drr_main_f32(const float* __restrict__ volt,
                                                       const float* __restrict__ batch,
                                                       float* __restrict__ raw,
                                                       unsigned* __restrict__ mm) {
    const int tid  = threadIdx.x;
    const int lane = tid & 63;
    const int seg  = tid >> 6;
    const int tile = blockIdx.x;
    const int b    = tile >> 10;
    const int ti   = tile & 1023;
    const int u    = ((ti & 15) << 4) + (lane & 15);
    const int v    = ((ti >> 4) << 2) + (lane >> 4);

    float sx, sy, sz;
    RayCfg A, B;
    ray_setup2(batch, b, u, v, sx, sy, sz, A, B);

    const float tstep = 1.0f / 255.0f;
    float sum = 0.0f;
    for (int k = A.k_lo + seg; k <= A.k_hi; k += 4)
        sum += tri_sample_f32(volt, sx, sy, sz, A, (float)k * tstep);

    __shared__ float part[4][64];
    part[seg][lane] = sum;
    __syncthreads();

    if (tid < 64) {
        const float s = part[0][lane] + part[1][lane] + part[2][lane] + part[3][lane];
        const float rawv = s * (A.length * (1.0f / 256.0f));
        raw[(b << 16) + (v << 8) + u] = rawv;
        float mn = rawv, mx = rawv;
        #pragma unroll
        for (int off = 32; off >= 1; off >>= 1) {
            mn = fminf(mn, __shfl_xor(mn, off));
            mx = fmaxf(mx, __shfl_xor(mx, off));
        }
        if (lane == 0) {
            atomicMin(&mm[2 * b + 0], __float_as_uint(mn));
            atomicMax(&mm[2 * b + 1], __float_as_uint(mx));
        }
    }
}

__global__ __launch_bounds__(256) void drr_norm_mm(float* __restrict__ img,
                                                   const unsigned* __restrict__ mm) {
    const int gid = blockIdx.x * 256 + threadIdx.x;
    const int b   = gid >> 16;
    const float mn  = __uint_as_float(mm[2 * b + 0]);
    const float mx  = __uint_as_float(mm[2 * b + 1]);
    const float inv = 1.0f / (mx - mn);
    img[gid] = 1.0f - (img[gid] - mn) * inv;
}

extern "C" void kernel_launch(void* const* d_in, const int* in_sizes, int n_in,
                              void* d_out, int out_size, void* d_ws, size_t ws_size,
                              hipStream_t stream) {
    const float* vol   = (const float*)d_in[0];
    const float* batch = (const float*)d_in[1];
    float* out         = (float*)d_out;

    if (ws_size >= QUAD_BYTES + 4096) {
        uint2* vq   = (uint2*)d_ws;
        float* part = (float*)((char*)d_ws + QUAD_BYTES);
        drr_pack_q<<<5160, 256, 0, stream>>>(vol, vq, out);
        drr_main_q<<<4096, 256, 0, stream>>>(vq, batch, out);
        drr_minmax<<<512, 256, 0, stream>>>(out, part);
        drr_norm<<<512, 256, 0, stream>>>(out, part);
    } else if (ws_size >= (size_t)PAIR_BYTES + 4096) {
        __half2* vhp  = (__half2*)d_ws;
        float*   part = (float*)((char*)d_ws + PAIR_BYTES);
        drr_pack<<<4096, 256, 0, stream>>>(vol, vhp, out);
        drr_main_pk3<<<4096, 256, 0, stream>>>(vhp, batch, out);
        drr_minmax<<<512, 256, 0, stream>>>(out, part);
        drr_norm<<<512, 256, 0, stream>>>(out, part);
    } else {
        float*    volt = (float*)d_ws;
        unsigned* mm   = (unsigned*)((char*)d_ws + VOL_BYTES);
        drr_init_mm<<<1, 64, 0, stream>>>(mm);
        drr_transpose<<<4096, 256, 0, stream>>>(vol, volt);
        drr_main_f32<<<2048, 256, 0, stream>>>(volt, batch, out, mm);
        drr_norm_mm<<<512, 256, 0, stream>>>(out, mm);
    }
}

// Round 17
// 79.330 us; speedup vs baseline: 1.3409x; 1.3409x over previous
//
#include <hip/hip_runtime.h>
#include <hip/hip_fp16.h>

// DRR ray-casting for MI355X — round 17.
// r16: quad tier's main worked (~37 us) but pack_q (64 us, 206 MB traffic)
// ate the gain — quad trades main-time for pack-bytes ~1:1, can't beat pair.
// r17 = r15 pair tier (proven 80.1) + loop-split k-loop in main (slow/fast/
// slow ranges, same iteration order -> bit-identical; removes per-iter branch).

static __device__ __constant__ float kPX     = 1.6875f;
static __device__ __constant__ float kPIERCE = 216.0f;
static __device__ __constant__ float kSAD    = 742.5f;
static __device__ __constant__ float kDAD    = 517.15f;

#define VOL_BYTES   (256u * 256u * 256u * 4u)
#define PAIR_R      258u
#define PAIR_ELEMS  (256u * 256u * PAIR_R)
#define PAIR_BYTES  (PAIR_ELEMS * 4u)

typedef __fp16 half2_raw __attribute__((ext_vector_type(2)));

__global__ void drr_init_mm(unsigned* mm) {
    int i = threadIdx.x;
    if (i < 4) mm[i] = (i & 1) ? 0u : 0x7F800000u;
}

// ---------------- pack: vol[x][y][z] -> vhp[z][y][i] = (v[i-1], v[i]) fp16 ---
// r15-proven body. Also zeroes raw (for main's atomic partial sums).
__global__ __launch_bounds__(256) void drr_pack(const float* __restrict__ vol,
                                                __half2* __restrict__ vhp,
                                                float* __restrict__ raw) {
    const int bid = blockIdx.x;
    if (threadIdx.x < 32)
        raw[(bid << 5) + threadIdx.x] = 0.0f;

    __shared__ float tile[65][65];
    const int y    = bid >> 4;
    const int t4   = bid & 15;
    const int x0   = (t4 & 3) << 6;
    const int z0   = (t4 >> 2) << 6;

    const int rr = threadIdx.x >> 4;
    const int cc = threadIdx.x & 15;
    #pragma unroll
    for (int base = 0; base < 80; base += 16) {
        const int r = base + rr;
        if (r < 65) {
            const int x = x0 - 1 + r;
            float4 f = make_float4(0.0f, 0.0f, 0.0f, 0.0f);
            if (x >= 0)
                f = *(const float4*)&vol[(x << 16) | (y << 8) | (z0 + (cc << 2))];
            tile[r][(cc << 2) + 0] = f.x;
            tile[r][(cc << 2) + 1] = f.y;
            tile[r][(cc << 2) + 2] = f.z;
            tile[r][(cc << 2) + 3] = f.w;
        }
    }
    __syncthreads();

    const int lane = threadIdx.x & 63;
    const int row4 = threadIdx.x >> 6;
    for (int r = row4; r < 64; r += 4) {
        const int z = z0 + r;
        const unsigned base = (unsigned)((z << 8) | y) * PAIR_R;
        vhp[base + x0 + lane] =
            __halves2half2(__float2half(tile[lane][r]), __float2half(tile[lane + 1][r]));
    }
    if ((t4 & 3) == 3) {
        for (int r = row4; r < 64; r += 4) {
            const int z = z0 + r;
            const unsigned base = (unsigned)((z << 8) | y) * PAIR_R;
            if (lane == 0) {
                vhp[base + 256] = __halves2half2(__float2half(tile[64][r]), __float2half(0.0f));
                vhp[base + 257] = __halves2half2(__float2half(0.0f), __float2half(0.0f));
            }
        }
    }
}

// ---------------- geometry -------------------------------------------------
__device__ __forceinline__ void slab(float s, float r, float lo, float hi,
                                     float& tlo, float& thi) {
    if (fabsf(r) > 1e-8f) {
        const float inv = 1.0f / r;
        const float ta  = (lo - s) * inv;
        const float tb  = (hi - s) * inv;
        tlo = fmaxf(tlo, fminf(ta, tb));
        thi = fminf(thi, fmaxf(ta, tb));
    } else if (s < lo || s > hi) {
        tlo = 2.0f; thi = -1.0f;
    }
}

struct RayCfg {
    float rx, ry, rz, length;
    int k_lo, k_hi;   // loose window (outside: exactly zero via masks)
    int s_lo, s_hi;   // strict window (inside: all masks 1, no clamps)
};

__device__ __forceinline__ void cfg_windows(float sx, float sy, float sz, RayCfg& c) {
    float tlo = 0.0f, thi = 1.0f;
    slab(sx, c.rx, -1.02f, 256.02f, tlo, thi);
    slab(sy, c.ry, -1.02f, 256.02f, tlo, thi);
    slab(sz, c.rz, -1.02f, 256.02f, tlo, thi);
    c.k_lo = 0; c.k_hi = -1;
    if (thi >= tlo) {
        c.k_lo = max(0,   (int)ceilf(tlo * 255.0f - 1e-3f));
        c.k_hi = min(255, (int)floorf(thi * 255.0f + 1e-3f));
    }
    float slo = 0.0f, shi = 1.0f;
    slab(sx, c.rx, 0.01f, 254.99f, slo, shi);
    slab(sy, c.ry, 0.01f, 254.99f, slo, shi);
    slab(sz, c.rz, 0.01f, 254.99f, slo, shi);
    c.s_lo = 1; c.s_hi = -1;
    if (shi >= slo) {
        c.s_lo = (int)ceilf(slo * 255.0f + 1e-3f);
        c.s_hi = (int)floorf(shi * 255.0f - 1e-3f);
    }
}

__device__ __forceinline__ void ray_setup2(const float* __restrict__ batch,
                                           int b, int u, int v0,
                                           float& sx, float& sy, float& sz,
                                           RayCfg& A, RayCfg& B) {
    const float a  = batch[b * 6 + 0];
    const float be = batch[b * 6 + 1];
    const float g  = batch[b * 6 + 2];
    const float tx = batch[b * 6 + 3];
    const float ty = batch[b * 6 + 4];
    const float tz = batch[b * 6 + 5];

    float sa, ca, sb, cb, sg, cg;
    sincosf(a, &sa, &ca);
    sincosf(be, &sb, &cb);
    sincosf(g, &sg, &cg);

    const float R00 = ca * cb;
    const float R01 = ca * sb * sg - sa * cg;
    const float R02 = sa * sg + ca * sb * cg;
    const float R10 = sa * cb;
    const float R11 = ca * cg + sa * sb * sg;
    const float R12 = sa * sb * cg - ca * sg;
    const float R20 = -sb;
    const float R21 = cb * sg;
    const float R22 = cb * cg;

    sx = 128.0f + tx + kSAD * R02;
    sy = 128.0f + ty + kSAD * R12;
    sz = 128.0f + tz + kSAD * R22;

    const float uu = u * kPX - kPIERCE;
    const float vv = v0 * kPX - kPIERCE;
    A.rx = uu * R00 + vv * R01 - (kSAD + kDAD) * R02;
    A.ry = uu * R10 + vv * R11 - (kSAD + kDAD) * R12;
    A.rz = uu * R20 + vv * R21 - (kSAD + kDAD) * R22;
    B.rx = A.rx + kPX * R01;
    B.ry = A.ry + kPX * R11;
    B.rz = A.rz + kPX * R21;
    A.length = sqrtf(A.rx * A.rx + A.ry * A.ry + A.rz * A.rz);
    B.length = sqrtf(B.rx * B.rx + B.ry * B.ry + B.rz * B.rz);
    cfg_windows(sx, sy, sz, A);
    cfg_windows(sx, sy, sz, B);
}

__device__ __forceinline__ float xdoth(__half2 q, half2_raw w) {
    return __builtin_amdgcn_fdot2(__builtin_bit_cast(half2_raw, q), w, 0.0f, false);
}

__device__ __forceinline__ float tri_fast(const __half2* __restrict__ vhp,
                                          float sx, float sy, float sz,
                                          const RayCfg& c, float t) {
    const float px = fmaf(t, c.rx, sx);
    const float py = fmaf(t, c.ry, sy);
    const float pz = fmaf(t, c.rz, sz);
    const float fx = floorf(px), fy = floorf(py), fz = floorf(pz);
    const int ix = (int)fx, iy = (int)fy, iz = (int)fz;
    const float wx = px - fx, wy = py - fy, wz = pz - fz;

    const unsigned base = (unsigned)iz * 66048u + (unsigned)iy * 258u + (unsigned)(ix + 1);
    const __half2 q00 = vhp[base];
    const __half2 q01 = vhp[base + 66048u];
    const __half2 q10 = vhp[base + 258u];
    const __half2 q11 = vhp[base + 66306u];

    const half2_raw wxh = __builtin_amdgcn_cvt_pkrtz(1.0f - wx, wx);
    const float a00 = xdoth(q00, wxh);
    const float a01 = xdoth(q01, wxh);
    const float a10 = xdoth(q10, wxh);
    const float a11 = xdoth(q11, wxh);

    const float wy0 = 1.0f - wy, wz0 = 1.0f - wz;
    return (a00 * wz0 + a01 * wz) * wy0 + (a10 * wz0 + a11 * wz) * wy;
}

__device__ __forceinline__ float tri_slow(const __half2* __restrict__ vhp,
                                          float sx, float sy, float sz,
                                          const RayCfg& c, float t) {
    const float px = fmaf(t, c.rx, sx);
    const float py = fmaf(t, c.ry, sy);
    const float pz = fmaf(t, c.rz, sz);
    const float fx = floorf(px), fy = floorf(py), fz = floorf(pz);
    const int ix = (int)fx, iy = (int)fy, iz = (int)fz;
    const float wx = px - fx, wy = py - fy, wz = pz - fz;

    const float mx0 = ((unsigned)ix       < 256u) ? 1.0f : 0.0f;
    const float mx1 = ((unsigned)(ix + 1) < 256u) ? 1.0f : 0.0f;
    const float my0 = ((unsigned)iy       < 256u) ? 1.0f : 0.0f;
    const float my1 = ((unsigned)(iy + 1) < 256u) ? 1.0f : 0.0f;
    const float mz0 = ((unsigned)iz       < 256u) ? 1.0f : 0.0f;
    const float mz1 = ((unsigned)(iz + 1) < 256u) ? 1.0f : 0.0f;

    const int i  = min(max(ix + 1, 0), 257);
    const int y0 = min(max(iy,     0), 255);
    const int y1 = min(max(iy + 1, 0), 255);
    const int z0 = min(max(iz,     0), 255);
    const int z1 = min(max(iz + 1, 0), 255);

    const unsigned zt0 = (unsigned)z0 * 66048u;
    const unsigned zt1 = (unsigned)z1 * 66048u;
    const unsigned yt0 = (unsigned)y0 * 258u;
    const unsigned yt1 = (unsigned)y1 * 258u;

    const __half2 q00 = vhp[zt0 + yt0 + i];
    const __half2 q01 = vhp[zt1 + yt0 + i];
    const __half2 q10 = vhp[zt0 + yt1 + i];
    const __half2 q11 = vhp[zt1 + yt1 + i];

    const half2_raw wxh = __builtin_amdgcn_cvt_pkrtz((1.0f - wx) * mx0, wx * mx1);
    const float a00 = xdoth(q00, wxh);
    const float a01 = xdoth(q01, wxh);
    const float a10 = xdoth(q10, wxh);
    const float a11 = xdoth(q11, wxh);

    const float wy0 = (1.0f - wy) * my0, wy1 = wy * my1;
    const float wz0 = (1.0f - wz) * mz0, wz1 = wz * mz1;
    return (a00 * wz0 + a01 * wz1) * wy0 + (a10 * wz0 + a11 * wz1) * wy1;
}

// Grid = 4096 = (1024 tiles) x (4 k-quarters); 16x8 tile, 2 v-px per lane.
// k-loop SPLIT into slow/fast/slow ranges (same iteration order as the r15
// branch version -> bit-identical sums; no per-iteration window compare).
__global__ __launch_bounds__(256, 8) void drr_main_pk3(const __half2* __restrict__ vhp,
                                                       const float* __restrict__ batch,
                                                       float* __restrict__ raw) {
    const int tid  = threadIdx.x;
    const int lane = tid & 63;
    const int seg  = tid >> 6;

    const int kq   = blockIdx.x & 3;
    const int tile = blockIdx.x >> 2;
    const int b    = tile >> 9;
    const int ti   = tile & 511;
    const int u    = ((ti & 15) << 4) + (lane & 15);
    const int v0   = ((ti >> 4) << 3) + ((lane >> 4) << 1);

    float sx, sy, sz;
    RayCfg A, B;
    ray_setup2(batch, b, u, v0, sx, sy, sz, A, B);

    const int klo = min(A.k_lo, B.k_lo);
    const int khi = max(A.k_hi, B.k_hi);
    const int slo = max(A.s_lo, B.s_lo);
    const int shi = min(A.s_hi, B.s_hi);

    const float tstep = 1.0f / 255.0f;
    float sA = 0.0f, sB = 0.0f;
    int k = klo + (kq << 2) + seg;

    // head: k < slo (boundary)
    for (; k <= khi && k < slo; k += 16) {
        const float t = (float)k * tstep;
        sA += tri_slow(vhp, sx, sy, sz, A, t);
        sB += tri_slow(vhp, sx, sy, sz, B, t);
    }
    // middle: slo <= k <= min(khi, shi) (interior, branch-free)
    const int mhi = min(khi, shi);
    for (; k <= mhi; k += 16) {
        const float t = (float)k * tstep;
        sA += tri_fast(vhp, sx, sy, sz, A, t);
        sB += tri_fast(vhp, sx, sy, sz, B, t);
    }
    // tail: k > shi (boundary)
    for (; k <= khi; k += 16) {
        const float t = (float)k * tstep;
        sA += tri_slow(vhp, sx, sy, sz, A, t);
        sB += tri_slow(vhp, sx, sy, sz, B, t);
    }

    __shared__ float pA[4][64], pB[4][64];
    pA[seg][lane] = sA;
    pB[seg][lane] = sB;
    __syncthreads();

    if (tid < 64) {
        const float tA = pA[0][lane] + pA[1][lane] + pA[2][lane] + pA[3][lane];
        const float tB = pB[0][lane] + pB[1][lane] + pB[2][lane] + pB[3][lane];
        if (tA != 0.0f)
            atomicAdd(&raw[(b << 16) + (v0 << 8) + u],       tA * (A.length * (1.0f / 256.0f)));
        if (tB != 0.0f)
            atomicAdd(&raw[(b << 16) + ((v0 + 1) << 8) + u], tB * (B.length * (1.0f / 256.0f)));
    }
}

// ---------------- minmax / norm (r14 proven) -------------------------------
__global__ __launch_bounds__(256) void drr_minmax(const float* __restrict__ raw,
                                                  float* __restrict__ part) {
    __shared__ float smn[4], smx[4];
    const int gid = blockIdx.x * 256 + threadIdx.x;
    const float x = raw[gid];
    float mn = x, mx = x;
    #pragma unroll
    for (int off = 32; off >= 1; off >>= 1) {
        mn = fminf(mn, __shfl_xor(mn, off));
        mx = fmaxf(mx, __shfl_xor(mx, off));
    }
    if ((threadIdx.x & 63) == 0) {
        smn[threadIdx.x >> 6] = mn;
        smx[threadIdx.x >> 6] = mx;
    }
    __syncthreads();
    if (threadIdx.x == 0) {
        part[2 * blockIdx.x + 0] = fminf(fminf(smn[0], smn[1]), fminf(smn[2], smn[3]));
        part[2 * blockIdx.x + 1] = fmaxf(fmaxf(smx[0], smx[1]), fmaxf(smx[2], smx[3]));
    }
}

__global__ __launch_bounds__(256) void drr_norm(float* __restrict__ img,
                                                const float* __restrict__ part) {
    __shared__ float smn[4], smx[4], fmn, fmx;
    const int b = blockIdx.x >> 8;
    const int pi = (b << 8) + threadIdx.x;
    float mn = part[2 * pi + 0];
    float mx = part[2 * pi + 1];
    #pragma unroll
    for (int off = 32; off >= 1; off >>= 1) {
        mn = fminf(mn, __shfl_xor(mn, off));
        mx = fmaxf(mx, __shfl_xor(mx, off));
    }
    if ((threadIdx.x & 63) == 0) {
        smn[threadIdx.x >> 6] = mn;
        smx[threadIdx.x >> 6] = mx;
    }
    __syncthreads();
    if (threadIdx.x == 0) {
        fmn = fminf(fminf(smn[0], smn[1]), fminf(smn[2], smn[3]));
        fmx = fmaxf(fmaxf(smx[0], smx[1]), fmaxf(smx[2], smx[3]));
    }
    __syncthreads();

    const int gid = blockIdx.x * 256 + threadIdx.x;
    const float inv = 1.0f / (fmx - fmn);
    img[gid] = 1.0f - (img[gid] - fmn) * inv;
}

// ---------------- f32 fallback (smallest ws) -------------------------------
__global__ __launch_bounds__(256) void drr_transpose(const float* __restrict__ vol,
                                                     float* __restrict__ volt) {
    __shared__ float tile[64][65];
    const int bid  = blockIdx.x;
    const int y    = bid >> 4;
    const int t4   = bid & 15;
    const int x0   = (t4 & 3) << 6;
    const int z0   = (t4 >> 2) << 6;
    const int lane = threadIdx.x & 63;
    const int row4 = threadIdx.x >> 6;

    #pragma unroll
    for (int i = 0; i < 16; ++i) {
        const int xr = (i << 2) + row4;
        tile[xr][lane] = vol[((x0 + xr) << 16) | (y << 8) | (z0 + lane)];
    }
    __syncthreads();
    #pragma unroll
    for (int i = 0; i < 16; ++i) {
        const int zr = (i << 2) + row4;
        volt[((z0 + zr) << 16) | (y << 8) | (x0 + lane)] = tile[lane][zr];
    }
}

__device__ __forceinline__ float tri_sample_f32(const float* __restrict__ vol,
                                                float sx, float sy, float sz,
                                                const RayCfg& c, float t) {
    const float px = fmaf(t, c.rx, sx);
    const float py = fmaf(t, c.ry, sy);
    const float pz = fmaf(t, c.rz, sz);
    const float fx = floorf(px), fy = floorf(py), fz = floorf(pz);
    const int ix = (int)fx, iy = (int)fy, iz = (int)fz;
    const float wx = px - fx, wy = py - fy, wz = pz - fz;
    const float mx0 = ((unsigned)ix       < 256u) ? 1.0f : 0.0f;
    const float mx1 = ((unsigned)(ix + 1) < 256u) ? 1.0f : 0.0f;
    const float my0 = ((unsigned)iy       < 256u) ? 1.0f : 0.0f;
    const float my1 = ((unsigned)(iy + 1) < 256u) ? 1.0f : 0.0f;
    const float mz0 = ((unsigned)iz       < 256u) ? 1.0f : 0.0f;
    const float mz1 = ((unsigned)(iz + 1) < 256u) ? 1.0f : 0.0f;
    const unsigned X0 = (unsigned)ix & 255u, X1 = (unsigned)(ix + 1) & 255u;
    const unsigned Y0 = ((unsigned)iy & 255u) << 8, Y1 = ((unsigned)(iy + 1) & 255u) << 8;
    const unsigned Z0 = ((unsigned)iz & 255u) << 16, Z1 = ((unsigned)(iz + 1) & 255u) << 16;
    const float v000 = vol[Z0 | Y0 | X0];
    const float v001 = vol[Z1 | Y0 | X0];
    const float v010 = vol[Z0 | Y1 | X0];
    const float v011 = vol[Z1 | Y1 | X0];
    const float v100 = vol[Z0 | Y0 | X1];
    const float v101 = vol[Z1 | Y0 | X1];
    const float v110 = vol[Z0 | Y1 | X1];
    const float v111 = vol[Z1 | Y1 | X1];
    const float wx0 = (1.0f - wx) * mx0, wx1 = wx * mx1;
    const float wy0 = (1.0f - wy) * my0, wy1 = wy * my1;
    const float wz0 = (1.0f - wz) * mz0, wz1 = wz * mz1;
    const float c00 = v000 * wz0 + v001 * wz1;
    const float c01 = v010 * wz0 + v011 * wz1;
    const float c10 = v100 * wz0 + v101 * wz1;
    const float c11 = v110 * wz0 + v111 * wz1;
    return (c00 * wy0 + c01 * wy1) * wx0 + (c10 * wy0 + c11 * wy1) * wx1;
}

__global__ __launch_bounds__(256, 4) void drr_main_f32(const float* __restrict__ volt,
                                                       const float* __restrict__ batch,
                                                       float* __restrict__ raw,
                                                       unsigned* __restrict__ mm) {
    const int tid  = threadIdx.x;
    const int lane = tid & 63;
    const int seg  = tid >> 6;
    const int tile = blockIdx.x;
    const int b    = tile >> 10;
    const int ti   = tile & 1023;
    const int u    = ((ti & 15) << 4) + (lane & 15);
    const int v    = ((ti >> 4) << 2) + (lane >> 4);

    float sx, sy, sz;
    RayCfg A, B;
    ray_setup2(batch, b, u, v, sx, sy, sz, A, B);

    const float tstep = 1.0f / 255.0f;
    float sum = 0.0f;
    for (int k = A.k_lo + seg; k <= A.k_hi; k += 4)
        sum += tri_sample_f32(volt, sx, sy, sz, A, (float)k * tstep);

    __shared__ float part[4][64];
    part[seg][lane] = sum;
    __syncthreads();

    if (tid < 64) {
        const float s = part[0][lane] + part[1][lane] + part[2][lane] + part[3][lane];
        const float rawv = s * (A.length * (1.0f / 256.0f));
        raw[(b << 16) + (v << 8) + u] = rawv;
        float mn = rawv, mx = rawv;
        #pragma unroll
        for (int off = 32; off >= 1; off >>= 1) {
            mn = fminf(mn, __shfl_xor(mn, off));
            mx = fmaxf(mx, __shfl_xor(mx, off));
        }
        if (lane == 0) {
            atomicMin(&mm[2 * b + 0], __float_as_uint(mn));
            atomicMax(&mm[2 * b + 1], __float_as_uint(mx));
        }
    }
}

__global__ __launch_bounds__(256) void drr_norm_mm(float* __restrict__ img,
                                                   const unsigned* __restrict__ mm) {
    const int gid = blockIdx.x * 256 + threadIdx.x;
    const int b   = gid >> 16;
    const float mn  = __uint_as_float(mm[2 * b + 0]);
    const float mx  = __uint_as_float(mm[2 * b + 1]);
    const float inv = 1.0f / (mx - mn);
    img[gid] = 1.0f - (img[gid] - mn) * inv;
}

extern "C" void kernel_launch(void* const* d_in, const int* in_sizes, int n_in,
                              void* d_out, int out_size, void* d_ws, size_t ws_size,
                              hipStream_t stream) {
    const float* vol   = (const float*)d_in[0];
    const float* batch = (const float*)d_in[1];
    float* out         = (float*)d_out;

    if (ws_size >= (size_t)PAIR_BYTES + 4096) {
        __half2* vhp  = (__half2*)d_ws;
        float*   part = (float*)((char*)d_ws + PAIR_BYTES);
        drr_pack<<<4096, 256, 0, stream>>>(vol, vhp, out);
        drr_main_pk3<<<4096, 256, 0, stream>>>(vhp, batch, out);
        drr_minmax<<<512, 256, 0, stream>>>(out, part);
        drr_norm<<<512, 256, 0, stream>>>(out, part);
    } else {
        float*    volt = (float*)d_ws;
        unsigned* mm   = (unsigned*)((char*)d_ws + VOL_BYTES);
        drr_init_mm<<<1, 64, 0, stream>>>(mm);
        drr_transpose<<<4096, 256, 0, stream>>>(vol, volt);
        drr_main_f32<<<2048, 256, 0, stream>>>(volt, batch, out, mm);
        drr_norm_mm<<<512, 256, 0, stream>>>(out, mm);
    }
}